// Round 8
// baseline (857.352 us; speedup 1.0000x reference)
//
#include <hip/hip_runtime.h>
#include <hip/hip_bf16.h>
#include <math.h>

#define N_NODES 50000
#define N_EDGES 800000
#define IN_C 128
#define HID_C 96
#define OUT_C 64
#define BN_EPS 1e-5f

static __device__ __forceinline__ unsigned short f2b(float f) {
    __hip_bfloat16 b = __float2bfloat16(f);   // RNE
    return *reinterpret_cast<unsigned short*>(&b);
}
static __device__ __forceinline__ float b2f(unsigned short u) {
    return __uint_as_float((unsigned)u << 16);  // exact
}

// ---------------------------------------------------------------------------
// Register-tiled GEMM: h[N,J] = x[N,K] @ W[K,J], h written as BF16 (the
// gather table for the following aggregation — halves its L2-miss bytes).
// APPLY: fuse the PREVIOUS layer's BN finalize (from raw stats) + apply +
// ReLU into the x staging load. Tile: 64 nodes x J channels; W in LDS; x
// staged transposed in K-chunks of 32; thread computes a 4x4 register tile.
// ---------------------------------------------------------------------------
template <int K, int J, bool APPLY>
__global__ void gemm_tiled(const float* __restrict__ x,
                           const float* __restrict__ W,
                           const float* __restrict__ stats,  // [sum[K], sumsq[K]]
                           const float* __restrict__ gamma,
                           const float* __restrict__ beta,
                           unsigned short* __restrict__ h, int N) {
    constexpr int MT = 64, TM = 4, TN = 4, KB = 32;
    constexpr int TX = J / TN;       // 24 (J=96) or 16 (J=64)
    constexpr int XP = MT + 4;       // padded XsT row
    __shared__ __align__(16) float Ws[K * J];
    __shared__ __align__(16) float XsT[KB * XP];
    __shared__ float scsh_s[2 * K];  // BN scale/shift (APPLY only)

    int tid = threadIdx.x;
    int tx = tid % TX, ty = tid / TX;
    int tileBase = blockIdx.x * MT;

    if (APPLY && tid < K) {
        // bn_finalize fused: conv bias cancels inside BN (mean absorbs it).
        const float invN = 1.f / N_NODES;
        float mean = stats[tid] * invN;
        float var = stats[K + tid] * invN - mean * mean;
        float sc = gamma[tid] * rsqrtf(var + BN_EPS);
        scsh_s[tid] = sc;
        scsh_s[K + tid] = beta[tid] - mean * sc;
    }

    for (int i = tid; i < K * J / 4; i += blockDim.x)
        ((float4*)Ws)[i] = ((const float4*)W)[i];

    float4 acc[TM];
#pragma unroll
    for (int tm = 0; tm < TM; ++tm) acc[tm] = make_float4(0.f, 0.f, 0.f, 0.f);

    for (int k0 = 0; k0 < K; k0 += KB) {
        __syncthreads();   // covers scsh_s/Ws on iter 0, chunk reuse after
        for (int i = tid; i < MT * (KB / 4); i += blockDim.x) {
            int node = i / (KB / 4), kq = i % (KB / 4);
            int gn = min(tileBase + node, N - 1);
            float4 v = *(const float4*)(x + (size_t)gn * K + k0 + kq * 4);
            if (APPLY) {
                int kb = k0 + kq * 4;
                v.x = fmaxf(v.x * scsh_s[kb + 0] + scsh_s[K + kb + 0], 0.f);
                v.y = fmaxf(v.y * scsh_s[kb + 1] + scsh_s[K + kb + 1], 0.f);
                v.z = fmaxf(v.z * scsh_s[kb + 2] + scsh_s[K + kb + 2], 0.f);
                v.w = fmaxf(v.w * scsh_s[kb + 3] + scsh_s[K + kb + 3], 0.f);
            }
            XsT[(kq * 4 + 0) * XP + node] = v.x;
            XsT[(kq * 4 + 1) * XP + node] = v.y;
            XsT[(kq * 4 + 2) * XP + node] = v.z;
            XsT[(kq * 4 + 3) * XP + node] = v.w;
        }
        __syncthreads();
#pragma unroll 8
        for (int kk = 0; kk < KB; ++kk) {
            float4 a = *(const float4*)&XsT[kk * XP + ty * TM];
            float4 b = *(const float4*)&Ws[(k0 + kk) * J + tx * TN];
#pragma unroll
            for (int tm = 0; tm < TM; ++tm) {
                float av = ((const float*)&a)[tm];
                acc[tm].x += av * b.x;
                acc[tm].y += av * b.y;
                acc[tm].z += av * b.z;
                acc[tm].w += av * b.w;
            }
        }
    }
#pragma unroll
    for (int tm = 0; tm < TM; ++tm) {
        int n = tileBase + ty * TM + tm;
        if (n < N) {
            ushort4 o;
            o.x = f2b(acc[tm].x); o.y = f2b(acc[tm].y);
            o.z = f2b(acc[tm].z); o.w = f2b(acc[tm].w);
            *(ushort4*)(h + (size_t)n * J + tx * TN) = o;
        }
    }
}

// ---------------------------------------------------------------------------
// CSR build: histogram -> hierarchical scan -> block-owned binned fill.
// ---------------------------------------------------------------------------
__global__ void hist_kernel(const int* __restrict__ row, int* __restrict__ deg) {
    int e = blockIdx.x * blockDim.x + threadIdx.x;
    if (e < N_EDGES) atomicAdd(&deg[row[e]], 1);
}

#define SCAN_B 256
#define SCAN_NB ((N_NODES + SCAN_B - 1) / SCAN_B)   // 196

__global__ void scanA_kernel(const int* __restrict__ deg, int* __restrict__ part) {
    __shared__ int s[SCAN_B];
    int i = blockIdx.x * SCAN_B + threadIdx.x;
    s[threadIdx.x] = (i < N_NODES) ? deg[i] : 0;
    __syncthreads();
    for (int off = SCAN_B / 2; off > 0; off >>= 1) {
        if (threadIdx.x < off) s[threadIdx.x] += s[threadIdx.x + off];
        __syncthreads();
    }
    if (threadIdx.x == 0) part[blockIdx.x] = s[0];
}

__global__ void scanB_kernel(int* __restrict__ part, int* __restrict__ rowptr) {
    __shared__ int s[SCAN_B];
    int t = threadIdx.x;
    s[t] = (t < SCAN_NB) ? part[t] : 0;
    __syncthreads();
    for (int off = 1; off < SCAN_B; off <<= 1) {
        int v = 0;
        if (t >= off) v = s[t - off];
        __syncthreads();
        if (t >= off) s[t] += v;
        __syncthreads();
    }
    if (t < SCAN_NB) part[t] = (t == 0) ? 0 : s[t - 1];   // exclusive
    if (t == 0) rowptr[N_NODES] = s[SCAN_NB - 1];         // total = N_EDGES
}

__global__ void scanC_kernel(const int* __restrict__ deg,
                             const int* __restrict__ part,
                             int* __restrict__ rowptr) {
    __shared__ int s[SCAN_B];
    int t = threadIdx.x;
    int i = blockIdx.x * SCAN_B + t;
    int d = (i < N_NODES) ? deg[i] : 0;
    s[t] = d;
    __syncthreads();
    for (int off = 1; off < SCAN_B; off <<= 1) {
        int v = 0;
        if (t >= off) v = s[t - off];
        __syncthreads();
        if (t >= off) s[t] += v;
        __syncthreads();
    }
    if (i < N_NODES) rowptr[i] = part[blockIdx.x] + s[t] - d;   // exclusive
}

// Block-owned binned fill (R7 lesson: the global permutation scatter touches
// one 64B line per 8B write -> 52 MB writeback for 6.4 MB of data). Block b
// owns FILL_ROWS consecutive rows = one contiguous pairs window; it scans the
// whole edge list (int4-coalesced), stages its edges in LDS at their exact
// CSR offset (LDS atomics on per-row ranks), then flushes LDS->global fully
// coalesced. CAP = mean + ~20 sigma; statistical overflow falls back to a
// direct (rare) global write.
#define FILL_BLOCKS 125
#define FILL_ROWS   (N_NODES / FILL_BLOCKS)   // 400
#define FILL_CAP    8000                      // 64 KB LDS of int2

__global__ void fill_binned_kernel(const int* __restrict__ row,
                                   const int* __restrict__ col,
                                   const float* __restrict__ ew,
                                   const int* __restrict__ rowptr,
                                   int2* __restrict__ pairs) {
    __shared__ int2 buf[FILL_CAP];
    __shared__ int rank[FILL_ROWS];
    int tid = threadIdx.x;
    int lo = blockIdx.x * FILL_ROWS;
    int base = rowptr[lo];
    int cnt = rowptr[lo + FILL_ROWS] - base;

    for (int r = tid; r < FILL_ROWS; r += blockDim.x)
        rank[r] = rowptr[lo + r] - base;
    __syncthreads();

    const int4* row4 = (const int4*)row;
    for (int i = tid; i < N_EDGES / 4; i += blockDim.x) {
        int4 r4 = row4[i];
#pragma unroll
        for (int j = 0; j < 4; ++j) {
            int r = (j == 0) ? r4.x : (j == 1) ? r4.y : (j == 2) ? r4.z : r4.w;
            int rl = r - lo;
            if ((unsigned)rl < (unsigned)FILL_ROWS) {
                int e = i * 4 + j;
                int loff = atomicAdd(&rank[rl], 1);
                int2 p = make_int2(col[e], __float_as_int(ew[e]));
                if (loff < FILL_CAP) buf[loff] = p;
                else pairs[base + loff] = p;   // statistical fallback
            }
        }
    }
    __syncthreads();
    int lim = min(cnt, FILL_CAP);
    for (int i = tid; i < lim; i += blockDim.x) pairs[base + i] = buf[i];
}

// ---------------------------------------------------------------------------
// CSR aggregation from the BF16 h-table. Free-running 256-thread blocks, no
// barrier (R6 lesson: a post-loop barrier halves achieved BW via max-degree
// stragglers). Gather = ushort4 (8B), exact <<16 convert, fp32 accumulate.
// LSM: fuse +b3 and log_softmax (16-lane shuffle groups), fp32 output.
// ---------------------------------------------------------------------------
template <int D, bool LSM>
__global__ void agg_csr_kernel(const unsigned short* __restrict__ h,
                               const int* __restrict__ rowptr,
                               const int2* __restrict__ pairs,
                               float* __restrict__ out,
                               const float* __restrict__ b3) {
    constexpr int G = D / 4;
    int t = blockIdx.x * blockDim.x + threadIdx.x;
    if (t >= N_NODES * G) return;
    int n = t / G, g = t % G;
    int beg = rowptr[n], end = rowptr[n + 1];
    float4 acc = make_float4(0.f, 0.f, 0.f, 0.f);
    for (int i = beg; i < end; ++i) {
        int2 p = pairs[i];
        float w = __int_as_float(p.y);
        ushort4 u = *(const ushort4*)(h + (size_t)p.x * D + g * 4);
        acc.x += w * b2f(u.x);
        acc.y += w * b2f(u.y);
        acc.z += w * b2f(u.z);
        acc.w += w * b2f(u.w);
    }

    if (LSM) {
        float4 bv = *(const float4*)(b3 + g * 4);
        float4 v = make_float4(acc.x + bv.x, acc.y + bv.y,
                               acc.z + bv.z, acc.w + bv.w);
        float m = fmaxf(fmaxf(v.x, v.y), fmaxf(v.z, v.w));
#pragma unroll
        for (int mask = 1; mask < 16; mask <<= 1)
            m = fmaxf(m, __shfl_xor(m, mask, 16));
        float s = expf(v.x - m) + expf(v.y - m) + expf(v.z - m) + expf(v.w - m);
#pragma unroll
        for (int mask = 1; mask < 16; mask <<= 1)
            s += __shfl_xor(s, mask, 16);
        float l = m + logf(s);
        *(float4*)(out + (size_t)n * D + g * 4) =
            make_float4(v.x - l, v.y - l, v.z - l, v.w - l);
    } else {
        *(float4*)(out + (size_t)n * D + g * 4) = acc;
    }
}

// ---------------------------------------------------------------------------
// BN stats (standalone, register-accumulation). Block = 384 threads =
// 16 rows x 24 groups; thread owns 4 fixed channels.
// ---------------------------------------------------------------------------
#define STATS_BLOCKS 250

template <int D>
__global__ void bn_stats_kernel(const float* __restrict__ a,
                                float* __restrict__ sums, int N) {
    constexpr int G = D / 4;       // 24
    constexpr int ROWS = 384 / G;  // 16
    int t = threadIdx.x;
    int g = t % G, r0 = t / G;
    float4 s4 = make_float4(0.f, 0.f, 0.f, 0.f);
    float4 q4 = make_float4(0.f, 0.f, 0.f, 0.f);
    for (int r = blockIdx.x * ROWS + r0; r < N; r += gridDim.x * ROWS) {
        float4 v = *(const float4*)(a + (size_t)r * D + g * 4);
        s4.x += v.x; s4.y += v.y; s4.z += v.z; s4.w += v.w;
        q4.x += v.x * v.x; q4.y += v.y * v.y; q4.z += v.z * v.z; q4.w += v.w * v.w;
    }
    __shared__ __align__(16) float sh[2 * ROWS * D];
    *(float4*)&sh[r0 * D + g * 4] = s4;
    *(float4*)&sh[ROWS * D + r0 * D + g * 4] = q4;
    __syncthreads();
    if (t < D) {
        float s0 = 0.f, s1 = 0.f;
#pragma unroll
        for (int k = 0; k < ROWS; ++k) {
            s0 += sh[k * D + t];
            s1 += sh[ROWS * D + k * D + t];
        }
        atomicAdd(&sums[t], s0);
        atomicAdd(&sums[D + t], s1);
    }
}

extern "C" void kernel_launch(void* const* d_in, const int* in_sizes, int n_in,
                              void* d_out, int out_size, void* d_ws, size_t ws_size,
                              hipStream_t stream) {
    const float* x   = (const float*)d_in[0];
    const float* ew  = (const float*)d_in[1];
    const int*   row = (const int*)d_in[2];
    const int*   col = (const int*)d_in[3];
    const float* W1  = (const float*)d_in[4];
    // b1 = d_in[5], b2 = d_in[7]: cancel inside BatchNorm (see gemm_tiled).
    const float* W2  = (const float*)d_in[6];
    const float* W3  = (const float*)d_in[8];
    const float* b3  = (const float*)d_in[9];
    const float* g1  = (const float*)d_in[10];
    const float* be1 = (const float*)d_in[11];
    const float* g2  = (const float*)d_in[12];
    const float* be2 = (const float*)d_in[13];
    float* out = (float*)d_out;

    // Workspace: B fp32[N*96] | A bf16[N*96] | stats1[192] | stats2[192] |
    //            pairs[E int2] | rowptr[N+1] | deg[N] | part[SCAN_NB]
    float*          B      = (float*)d_ws;
    unsigned short* A      = (unsigned short*)(B + (size_t)N_NODES * HID_C);
    float*          stats1 = (float*)(A + (size_t)N_NODES * HID_C);
    float*          stats2 = stats1 + 2 * HID_C;
    int2*           pairs  = (int2*)(stats2 + 2 * HID_C);
    int*            rowptr = (int*)(pairs + N_EDGES);
    int*            deg    = rowptr + (N_NODES + 1);
    int*            part   = deg + N_NODES;

    const int T = 256;
    const int gridE   = (N_EDGES + T - 1) / T;
    const int gridA96 = (N_NODES * (HID_C / 4) + T - 1) / T;
    const int gridA64 = (N_NODES * (OUT_C / 4) + T - 1) / T;
    const int gridG   = (N_NODES + 63) / 64;

    // ---- CSR build + stats zero ----
    hipMemsetAsync(deg, 0, N_NODES * sizeof(int), stream);
    hipMemsetAsync(stats1, 0, 4 * HID_C * sizeof(float), stream);
    hist_kernel<<<gridE, T, 0, stream>>>(row, deg);
    scanA_kernel<<<SCAN_NB, SCAN_B, 0, stream>>>(deg, part);
    scanB_kernel<<<1, SCAN_B, 0, stream>>>(part, rowptr);
    scanC_kernel<<<SCAN_NB, SCAN_B, 0, stream>>>(deg, part, rowptr);
    fill_binned_kernel<<<FILL_BLOCKS, T, 0, stream>>>(row, col, ew, rowptr, pairs);

    // ---- Layer 1: GCNConv(128->96) -> bf16 A; agg -> fp32 B; BN1 stats ----
    gemm_tiled<IN_C, HID_C, false><<<gridG, (HID_C / 4) * 16, 0, stream>>>(
        x, W1, nullptr, nullptr, nullptr, A, N_NODES);
    agg_csr_kernel<HID_C, false><<<gridA96, T, 0, stream>>>(
        A, rowptr, pairs, B, nullptr);
    bn_stats_kernel<HID_C><<<STATS_BLOCKS, 384, 0, stream>>>(B, stats1, N_NODES);

    // ---- Layer 2: gemm fuses BN1 finalize+apply+ReLU; agg; BN2 stats ----
    gemm_tiled<HID_C, HID_C, true><<<gridG, (HID_C / 4) * 16, 0, stream>>>(
        B, W2, stats1, g1, be1, A, N_NODES);
    agg_csr_kernel<HID_C, false><<<gridA96, T, 0, stream>>>(
        A, rowptr, pairs, B, nullptr);
    bn_stats_kernel<HID_C><<<STATS_BLOCKS, 384, 0, stream>>>(B, stats2, N_NODES);

    // ---- Layer 3: gemm fuses BN2; agg fuses +b3 and log_softmax -> out ----
    gemm_tiled<HID_C, OUT_C, true><<<gridG, (OUT_C / 4) * 16, 0, stream>>>(
        B, W3, stats2, g2, be2, A, N_NODES);
    agg_csr_kernel<OUT_C, true><<<gridA64, T, 0, stream>>>(
        A, rowptr, pairs, out, b3);
}

// Round 9
// 374.228 us; speedup vs baseline: 2.2910x; 2.2910x over previous
//
#include <hip/hip_runtime.h>
#include <hip/hip_bf16.h>
#include <math.h>

#define N_NODES 50000
#define N_EDGES 800000
#define IN_C 128
#define HID_C 96
#define OUT_C 64
#define BN_EPS 1e-5f

static __device__ __forceinline__ unsigned short f2b(float f) {
    __hip_bfloat16 b = __float2bfloat16(f);   // RNE
    return *reinterpret_cast<unsigned short*>(&b);
}
static __device__ __forceinline__ float b2f(unsigned short u) {
    return __uint_as_float((unsigned)u << 16);  // exact
}

// ---------------------------------------------------------------------------
// Register-tiled GEMM: h[N,J] = x[N,K] @ W[K,J], h written as BF16 (the
// gather table for the following aggregation — halves its L2-miss bytes).
// APPLY: fuse the PREVIOUS layer's BN finalize (from raw stats) + apply +
// ReLU into the x staging load. Tile: 64 nodes x J channels; W in LDS; x
// staged transposed in K-chunks of 32; thread computes a 4x4 register tile.
// ---------------------------------------------------------------------------
template <int K, int J, bool APPLY>
__global__ void gemm_tiled(const float* __restrict__ x,
                           const float* __restrict__ W,
                           const float* __restrict__ stats,  // [sum[K], sumsq[K]]
                           const float* __restrict__ gamma,
                           const float* __restrict__ beta,
                           unsigned short* __restrict__ h, int N) {
    constexpr int MT = 64, TM = 4, TN = 4, KB = 32;
    constexpr int TX = J / TN;       // 24 (J=96) or 16 (J=64)
    constexpr int XP = MT + 4;       // padded XsT row
    __shared__ __align__(16) float Ws[K * J];
    __shared__ __align__(16) float XsT[KB * XP];
    __shared__ float scsh_s[2 * K];  // BN scale/shift (APPLY only)

    int tid = threadIdx.x;
    int tx = tid % TX, ty = tid / TX;
    int tileBase = blockIdx.x * MT;

    if (APPLY && tid < K) {
        // bn_finalize fused: conv bias cancels inside BN (mean absorbs it).
        const float invN = 1.f / N_NODES;
        float mean = stats[tid] * invN;
        float var = stats[K + tid] * invN - mean * mean;
        float sc = gamma[tid] * rsqrtf(var + BN_EPS);
        scsh_s[tid] = sc;
        scsh_s[K + tid] = beta[tid] - mean * sc;
    }

    for (int i = tid; i < K * J / 4; i += blockDim.x)
        ((float4*)Ws)[i] = ((const float4*)W)[i];

    float4 acc[TM];
#pragma unroll
    for (int tm = 0; tm < TM; ++tm) acc[tm] = make_float4(0.f, 0.f, 0.f, 0.f);

    for (int k0 = 0; k0 < K; k0 += KB) {
        __syncthreads();   // covers scsh_s/Ws on iter 0, chunk reuse after
        for (int i = tid; i < MT * (KB / 4); i += blockDim.x) {
            int node = i / (KB / 4), kq = i % (KB / 4);
            int gn = min(tileBase + node, N - 1);
            float4 v = *(const float4*)(x + (size_t)gn * K + k0 + kq * 4);
            if (APPLY) {
                int kb = k0 + kq * 4;
                v.x = fmaxf(v.x * scsh_s[kb + 0] + scsh_s[K + kb + 0], 0.f);
                v.y = fmaxf(v.y * scsh_s[kb + 1] + scsh_s[K + kb + 1], 0.f);
                v.z = fmaxf(v.z * scsh_s[kb + 2] + scsh_s[K + kb + 2], 0.f);
                v.w = fmaxf(v.w * scsh_s[kb + 3] + scsh_s[K + kb + 3], 0.f);
            }
            XsT[(kq * 4 + 0) * XP + node] = v.x;
            XsT[(kq * 4 + 1) * XP + node] = v.y;
            XsT[(kq * 4 + 2) * XP + node] = v.z;
            XsT[(kq * 4 + 3) * XP + node] = v.w;
        }
        __syncthreads();
#pragma unroll 8
        for (int kk = 0; kk < KB; ++kk) {
            float4 a = *(const float4*)&XsT[kk * XP + ty * TM];
            float4 b = *(const float4*)&Ws[(k0 + kk) * J + tx * TN];
#pragma unroll
            for (int tm = 0; tm < TM; ++tm) {
                float av = ((const float*)&a)[tm];
                acc[tm].x += av * b.x;
                acc[tm].y += av * b.y;
                acc[tm].z += av * b.z;
                acc[tm].w += av * b.w;
            }
        }
    }
#pragma unroll
    for (int tm = 0; tm < TM; ++tm) {
        int n = tileBase + ty * TM + tm;
        if (n < N) {
            ushort4 o;
            o.x = f2b(acc[tm].x); o.y = f2b(acc[tm].y);
            o.z = f2b(acc[tm].z); o.w = f2b(acc[tm].w);
            *(ushort4*)(h + (size_t)n * J + tx * TN) = o;
        }
    }
}

// ---------------------------------------------------------------------------
// CSR build: histogram -> hierarchical scan -> permutation-scatter fill.
// (R8 lesson: block-owned binned fill fixed write amplification but capped
// parallelism at 125 blocks scanning all edges each -> 10x slower. The
// scatter's 52 MB line-touch writeback at full parallelism is the better
// trade: 53 us.)
// ---------------------------------------------------------------------------
__global__ void hist_kernel(const int* __restrict__ row, int* __restrict__ deg) {
    int e = blockIdx.x * blockDim.x + threadIdx.x;
    if (e < N_EDGES) atomicAdd(&deg[row[e]], 1);
}

#define SCAN_B 256
#define SCAN_NB ((N_NODES + SCAN_B - 1) / SCAN_B)   // 196

__global__ void scanA_kernel(const int* __restrict__ deg, int* __restrict__ part) {
    __shared__ int s[SCAN_B];
    int i = blockIdx.x * SCAN_B + threadIdx.x;
    s[threadIdx.x] = (i < N_NODES) ? deg[i] : 0;
    __syncthreads();
    for (int off = SCAN_B / 2; off > 0; off >>= 1) {
        if (threadIdx.x < off) s[threadIdx.x] += s[threadIdx.x + off];
        __syncthreads();
    }
    if (threadIdx.x == 0) part[blockIdx.x] = s[0];
}

__global__ void scanB_kernel(int* __restrict__ part, int* __restrict__ rowptr) {
    __shared__ int s[SCAN_B];
    int t = threadIdx.x;
    s[t] = (t < SCAN_NB) ? part[t] : 0;
    __syncthreads();
    for (int off = 1; off < SCAN_B; off <<= 1) {
        int v = 0;
        if (t >= off) v = s[t - off];
        __syncthreads();
        if (t >= off) s[t] += v;
        __syncthreads();
    }
    if (t < SCAN_NB) part[t] = (t == 0) ? 0 : s[t - 1];   // exclusive
    if (t == 0) rowptr[N_NODES] = s[SCAN_NB - 1];         // total = N_EDGES
}

__global__ void scanC_kernel(const int* __restrict__ deg,
                             const int* __restrict__ part,
                             int* __restrict__ rowptr, int* __restrict__ pos) {
    __shared__ int s[SCAN_B];
    int t = threadIdx.x;
    int i = blockIdx.x * SCAN_B + t;
    int d = (i < N_NODES) ? deg[i] : 0;
    s[t] = d;
    __syncthreads();
    for (int off = 1; off < SCAN_B; off <<= 1) {
        int v = 0;
        if (t >= off) v = s[t - off];
        __syncthreads();
        if (t >= off) s[t] += v;
        __syncthreads();
    }
    if (i < N_NODES) {
        int r = part[blockIdx.x] + s[t] - d;   // exclusive
        rowptr[i] = r;
        pos[i] = r;
    }
}

__global__ void fill_kernel(const int* __restrict__ row, const int* __restrict__ col,
                            const float* __restrict__ ew, int* __restrict__ pos,
                            int2* __restrict__ pairs) {
    int e = blockIdx.x * blockDim.x + threadIdx.x;
    if (e >= N_EDGES) return;
    int idx = atomicAdd(&pos[row[e]], 1);
    pairs[idx] = make_int2(col[e], __float_as_int(ew[e]));
}

// ---------------------------------------------------------------------------
// CSR aggregation from the BF16 h-table. Free-running 256-thread blocks, no
// barrier (R6 lesson: a post-loop barrier halves achieved BW via max-degree
// stragglers). 2-way edge unroll for memory-level parallelism (latency-bound
// loop: R5 showed VALUBusy 7.5%, BW 45% of achievable). Gather = ushort4,
// exact <<16 convert, fp32 accumulate.
// LSM: fuse +b3 and log_softmax (16-lane shuffle groups), fp32 output.
// ---------------------------------------------------------------------------
template <int D, bool LSM>
__global__ void agg_csr_kernel(const unsigned short* __restrict__ h,
                               const int* __restrict__ rowptr,
                               const int2* __restrict__ pairs,
                               float* __restrict__ out,
                               const float* __restrict__ b3) {
    constexpr int G = D / 4;
    int t = blockIdx.x * blockDim.x + threadIdx.x;
    if (t >= N_NODES * G) return;
    int n = t / G, g = t % G;
    int beg = rowptr[n], end = rowptr[n + 1];
    float4 acc = make_float4(0.f, 0.f, 0.f, 0.f);
    float4 acc2 = make_float4(0.f, 0.f, 0.f, 0.f);
    int i = beg;
    for (; i + 1 < end; i += 2) {
        int2 p0 = pairs[i];
        int2 p1 = pairs[i + 1];
        ushort4 u0 = *(const ushort4*)(h + (size_t)p0.x * D + g * 4);
        ushort4 u1 = *(const ushort4*)(h + (size_t)p1.x * D + g * 4);
        float w0 = __int_as_float(p0.y), w1 = __int_as_float(p1.y);
        acc.x += w0 * b2f(u0.x); acc.y += w0 * b2f(u0.y);
        acc.z += w0 * b2f(u0.z); acc.w += w0 * b2f(u0.w);
        acc2.x += w1 * b2f(u1.x); acc2.y += w1 * b2f(u1.y);
        acc2.z += w1 * b2f(u1.z); acc2.w += w1 * b2f(u1.w);
    }
    if (i < end) {
        int2 p = pairs[i];
        float w = __int_as_float(p.y);
        ushort4 u = *(const ushort4*)(h + (size_t)p.x * D + g * 4);
        acc.x += w * b2f(u.x); acc.y += w * b2f(u.y);
        acc.z += w * b2f(u.z); acc.w += w * b2f(u.w);
    }
    acc.x += acc2.x; acc.y += acc2.y; acc.z += acc2.z; acc.w += acc2.w;

    if (LSM) {
        float4 bv = *(const float4*)(b3 + g * 4);
        float4 v = make_float4(acc.x + bv.x, acc.y + bv.y,
                               acc.z + bv.z, acc.w + bv.w);
        float m = fmaxf(fmaxf(v.x, v.y), fmaxf(v.z, v.w));
#pragma unroll
        for (int mask = 1; mask < 16; mask <<= 1)
            m = fmaxf(m, __shfl_xor(m, mask, 16));
        float s = expf(v.x - m) + expf(v.y - m) + expf(v.z - m) + expf(v.w - m);
#pragma unroll
        for (int mask = 1; mask < 16; mask <<= 1)
            s += __shfl_xor(s, mask, 16);
        float l = m + logf(s);
        *(float4*)(out + (size_t)n * D + g * 4) =
            make_float4(v.x - l, v.y - l, v.z - l, v.w - l);
    } else {
        *(float4*)(out + (size_t)n * D + g * 4) = acc;
    }
}

// ---------------------------------------------------------------------------
// BN stats (standalone, register-accumulation). Block = 384 threads =
// 16 rows x 24 groups; thread owns 4 fixed channels.
// ---------------------------------------------------------------------------
#define STATS_BLOCKS 250

template <int D>
__global__ void bn_stats_kernel(const float* __restrict__ a,
                                float* __restrict__ sums, int N) {
    constexpr int G = D / 4;       // 24
    constexpr int ROWS = 384 / G;  // 16
    int t = threadIdx.x;
    int g = t % G, r0 = t / G;
    float4 s4 = make_float4(0.f, 0.f, 0.f, 0.f);
    float4 q4 = make_float4(0.f, 0.f, 0.f, 0.f);
    for (int r = blockIdx.x * ROWS + r0; r < N; r += gridDim.x * ROWS) {
        float4 v = *(const float4*)(a + (size_t)r * D + g * 4);
        s4.x += v.x; s4.y += v.y; s4.z += v.z; s4.w += v.w;
        q4.x += v.x * v.x; q4.y += v.y * v.y; q4.z += v.z * v.z; q4.w += v.w * v.w;
    }
    __shared__ __align__(16) float sh[2 * ROWS * D];
    *(float4*)&sh[r0 * D + g * 4] = s4;
    *(float4*)&sh[ROWS * D + r0 * D + g * 4] = q4;
    __syncthreads();
    if (t < D) {
        float s0 = 0.f, s1 = 0.f;
#pragma unroll
        for (int k = 0; k < ROWS; ++k) {
            s0 += sh[k * D + t];
            s1 += sh[ROWS * D + k * D + t];
        }
        atomicAdd(&sums[t], s0);
        atomicAdd(&sums[D + t], s1);
    }
}

extern "C" void kernel_launch(void* const* d_in, const int* in_sizes, int n_in,
                              void* d_out, int out_size, void* d_ws, size_t ws_size,
                              hipStream_t stream) {
    const float* x   = (const float*)d_in[0];
    const float* ew  = (const float*)d_in[1];
    const int*   row = (const int*)d_in[2];
    const int*   col = (const int*)d_in[3];
    const float* W1  = (const float*)d_in[4];
    // b1 = d_in[5], b2 = d_in[7]: cancel inside BatchNorm (see gemm_tiled).
    const float* W2  = (const float*)d_in[6];
    const float* W3  = (const float*)d_in[8];
    const float* b3  = (const float*)d_in[9];
    const float* g1  = (const float*)d_in[10];
    const float* be1 = (const float*)d_in[11];
    const float* g2  = (const float*)d_in[12];
    const float* be2 = (const float*)d_in[13];
    float* out = (float*)d_out;

    // Workspace: B fp32[N*96] | A bf16[N*96] | stats1[192] | stats2[192] |
    //            pairs[E int2] | rowptr[N+1] | deg[N] | pos[N] | part[SCAN_NB]
    float*          B      = (float*)d_ws;
    unsigned short* A      = (unsigned short*)(B + (size_t)N_NODES * HID_C);
    float*          stats1 = (float*)(A + (size_t)N_NODES * HID_C);
    float*          stats2 = stats1 + 2 * HID_C;
    int2*           pairs  = (int2*)(stats2 + 2 * HID_C);
    int*            rowptr = (int*)(pairs + N_EDGES);
    int*            deg    = rowptr + (N_NODES + 1);
    int*            pos    = deg + N_NODES;
    int*            part   = pos + N_NODES;

    const int T = 256;
    const int gridE   = (N_EDGES + T - 1) / T;
    const int gridA96 = (N_NODES * (HID_C / 4) + T - 1) / T;
    const int gridA64 = (N_NODES * (OUT_C / 4) + T - 1) / T;
    const int gridG   = (N_NODES + 63) / 64;

    // ---- CSR build + stats zero ----
    hipMemsetAsync(deg, 0, N_NODES * sizeof(int), stream);
    hipMemsetAsync(stats1, 0, 4 * HID_C * sizeof(float), stream);
    hist_kernel<<<gridE, T, 0, stream>>>(row, deg);
    scanA_kernel<<<SCAN_NB, SCAN_B, 0, stream>>>(deg, part);
    scanB_kernel<<<1, SCAN_B, 0, stream>>>(part, rowptr);
    scanC_kernel<<<SCAN_NB, SCAN_B, 0, stream>>>(deg, part, rowptr, pos);
    fill_kernel<<<gridE, T, 0, stream>>>(row, col, ew, pos, pairs);

    // ---- Layer 1: GCNConv(128->96) -> bf16 A; agg -> fp32 B; BN1 stats ----
    gemm_tiled<IN_C, HID_C, false><<<gridG, (HID_C / 4) * 16, 0, stream>>>(
        x, W1, nullptr, nullptr, nullptr, A, N_NODES);
    agg_csr_kernel<HID_C, false><<<gridA96, T, 0, stream>>>(
        A, rowptr, pairs, B, nullptr);
    bn_stats_kernel<HID_C><<<STATS_BLOCKS, 384, 0, stream>>>(B, stats1, N_NODES);

    // ---- Layer 2: gemm fuses BN1 finalize+apply+ReLU; agg; BN2 stats ----
    gemm_tiled<HID_C, HID_C, true><<<gridG, (HID_C / 4) * 16, 0, stream>>>(
        B, W2, stats1, g1, be1, A, N_NODES);
    agg_csr_kernel<HID_C, false><<<gridA96, T, 0, stream>>>(
        A, rowptr, pairs, B, nullptr);
    bn_stats_kernel<HID_C><<<STATS_BLOCKS, 384, 0, stream>>>(B, stats2, N_NODES);

    // ---- Layer 3: gemm fuses BN2; agg fuses +b3 and log_softmax -> out ----
    gemm_tiled<HID_C, OUT_C, true><<<gridG, (OUT_C / 4) * 16, 0, stream>>>(
        B, W3, stats2, g2, be2, A, N_NODES);
    agg_csr_kernel<OUT_C, true><<<gridA64, T, 0, stream>>>(
        A, rowptr, pairs, out, b3);
}

// Round 10
// 343.919 us; speedup vs baseline: 2.4929x; 1.0881x over previous
//
#include <hip/hip_runtime.h>
#include <hip/hip_bf16.h>
#include <math.h>

#define N_NODES 50000
#define N_EDGES 800000
#define IN_C 128
#define HID_C 96
#define OUT_C 64
#define BN_EPS 1e-5f

typedef __attribute__((ext_vector_type(8))) short short8;   // 8 bf16 = 4 VGPRs
typedef __attribute__((ext_vector_type(4))) float f32x4;    // MFMA acc

static __device__ __forceinline__ unsigned short f2b(float f) {
    __hip_bfloat16 b = __float2bfloat16(f);   // RNE
    return *reinterpret_cast<unsigned short*>(&b);
}
static __device__ __forceinline__ float b2f(unsigned short u) {
    return __uint_as_float((unsigned)u << 16);  // exact
}

// ---------------------------------------------------------------------------
// Weight prep: W[K][J] fp32 -> Wt[J][K] bf16 (once per layer, ~48 KB).
// Lets the MFMA gemm stage both LDS tiles as contiguous row copies.
// ---------------------------------------------------------------------------
template <int K, int J>
__global__ void wprep_kernel(const float* __restrict__ W,
                             unsigned short* __restrict__ Wt) {
    int i = blockIdx.x * blockDim.x + threadIdx.x;   // i = j*K + k
    if (i < K * J) {
        int j = i / K, k = i % K;
        Wt[i] = f2b(W[k * J + j]);
    }
}

// ---------------------------------------------------------------------------
// MFMA GEMM: h[N,J] = x[N,K] @ W[K,J], bf16 inputs, fp32 accumulate, bf16 h.
// Block = 256 threads = 4 waves; tile = 64 nodes x J. Wave w owns nodes
// [w*16, w*16+16) and all J cols (J/16 n-tiles). LDS: Xs[64][K] bf16 rows
// (stride K+8: 16B-aligned rows, 2-way-free reads), Ws[J][K] bf16 from Wt.
// mfma_f32_16x16x32_bf16 layouts (HW-verified per docs):
//   A: lane holds X[m=lane&15][k=(lane>>4)*8+j]   (short8 = 8 consecutive k)
//   B: lane holds W[k=(lane>>4)*8+j][n=lane&15]   (= row n of W^T)
//   D: lane,reg r -> row m=(lane>>4)*4+r, col n=lane&15
// APPLY: previous layer's BN finalize+apply+ReLU fused into x staging.
// ---------------------------------------------------------------------------
template <int K, int J, bool APPLY>
__global__ __launch_bounds__(256)
void gemm_mfma(const float* __restrict__ x,
               const unsigned short* __restrict__ Wt,  // [J][K] bf16
               const float* __restrict__ stats,        // [sum[K], sumsq[K]]
               const float* __restrict__ gamma,
               const float* __restrict__ beta,
               unsigned short* __restrict__ h, int N) {
    constexpr int MT = 64;          // nodes per block
    constexpr int SK = K + 8;       // LDS row stride in bf16 (rows 16B-aligned)
    constexpr int NT = J / 16;      // n-tiles per wave
    __shared__ unsigned short Xs[MT * SK];
    __shared__ unsigned short Ws[J * SK];
    __shared__ float scsh_s[APPLY ? 2 * K : 2];

    int tid = threadIdx.x;
    int tileBase = blockIdx.x * MT;

    if (APPLY) {
        if (tid < K) {
            // conv bias cancels inside BN (mean absorbs it)
            const float invN = 1.f / N_NODES;
            float mean = stats[tid] * invN;
            float var = stats[K + tid] * invN - mean * mean;
            float sc = gamma[tid] * rsqrtf(var + BN_EPS);
            scsh_s[tid] = sc;
            scsh_s[K + tid] = beta[tid] - mean * sc;
        }
        __syncthreads();
    }

    // Stage x tile: fp32 global float4 -> (BN+ReLU) -> bf16 LDS row [node][k]
    for (int i = tid; i < MT * (K / 4); i += 256) {
        int node = i / (K / 4), kq = i % (K / 4);
        int gn = min(tileBase + node, N - 1);
        float4 v = *(const float4*)(x + (size_t)gn * K + kq * 4);
        if (APPLY) {
            int kb = kq * 4;
            v.x = fmaxf(v.x * scsh_s[kb + 0] + scsh_s[K + kb + 0], 0.f);
            v.y = fmaxf(v.y * scsh_s[kb + 1] + scsh_s[K + kb + 1], 0.f);
            v.z = fmaxf(v.z * scsh_s[kb + 2] + scsh_s[K + kb + 2], 0.f);
            v.w = fmaxf(v.w * scsh_s[kb + 3] + scsh_s[K + kb + 3], 0.f);
        }
        ushort4 o = make_ushort4(f2b(v.x), f2b(v.y), f2b(v.z), f2b(v.w));
        *(ushort4*)&Xs[node * SK + kq * 4] = o;
    }
    // Stage Wt: bf16 global ushort4 -> LDS row [j][k] (straight copy)
    for (int i = tid; i < J * (K / 4); i += 256) {
        int j = i / (K / 4), kq = i % (K / 4);
        *(ushort4*)&Ws[j * SK + kq * 4] =
            *(const ushort4*)(Wt + (size_t)j * K + kq * 4);
    }
    __syncthreads();

    int lane = tid & 63;
    int w = tid >> 6;
    int m16 = lane & 15;
    int quad = lane >> 4;

    f32x4 acc[NT];
#pragma unroll
    for (int nt = 0; nt < NT; ++nt) acc[nt] = (f32x4){0.f, 0.f, 0.f, 0.f};

    const unsigned short* xrow = &Xs[(w * 16 + m16) * SK];
#pragma unroll
    for (int k0 = 0; k0 < K; k0 += 32) {
        short8 a = *(const short8*)(xrow + k0 + quad * 8);
#pragma unroll
        for (int nt = 0; nt < NT; ++nt) {
            short8 b = *(const short8*)&Ws[(nt * 16 + m16) * SK + k0 + quad * 8];
            acc[nt] = __builtin_amdgcn_mfma_f32_16x16x32_bf16(a, b, acc[nt], 0, 0, 0);
        }
    }

#pragma unroll
    for (int nt = 0; nt < NT; ++nt) {
#pragma unroll
        for (int r = 0; r < 4; ++r) {
            int node = tileBase + w * 16 + quad * 4 + r;
            if (node < N)
                h[(size_t)node * J + nt * 16 + m16] = f2b(acc[nt][r]);
        }
    }
}

// ---------------------------------------------------------------------------
// CSR build: histogram -> hierarchical scan -> permutation-scatter fill.
// (R8 lesson: binned fill fixed write amplification but capped parallelism
// at 125 blocks -> 10x slower. The scatter at full parallelism wins: 52 us.)
// ---------------------------------------------------------------------------
__global__ void hist_kernel(const int* __restrict__ row, int* __restrict__ deg) {
    int e = blockIdx.x * blockDim.x + threadIdx.x;
    if (e < N_EDGES) atomicAdd(&deg[row[e]], 1);
}

#define SCAN_B 256
#define SCAN_NB ((N_NODES + SCAN_B - 1) / SCAN_B)   // 196

__global__ void scanA_kernel(const int* __restrict__ deg, int* __restrict__ part) {
    __shared__ int s[SCAN_B];
    int i = blockIdx.x * SCAN_B + threadIdx.x;
    s[threadIdx.x] = (i < N_NODES) ? deg[i] : 0;
    __syncthreads();
    for (int off = SCAN_B / 2; off > 0; off >>= 1) {
        if (threadIdx.x < off) s[threadIdx.x] += s[threadIdx.x + off];
        __syncthreads();
    }
    if (threadIdx.x == 0) part[blockIdx.x] = s[0];
}

__global__ void scanB_kernel(int* __restrict__ part, int* __restrict__ rowptr) {
    __shared__ int s[SCAN_B];
    int t = threadIdx.x;
    s[t] = (t < SCAN_NB) ? part[t] : 0;
    __syncthreads();
    for (int off = 1; off < SCAN_B; off <<= 1) {
        int v = 0;
        if (t >= off) v = s[t - off];
        __syncthreads();
        if (t >= off) s[t] += v;
        __syncthreads();
    }
    if (t < SCAN_NB) part[t] = (t == 0) ? 0 : s[t - 1];   // exclusive
    if (t == 0) rowptr[N_NODES] = s[SCAN_NB - 1];         // total = N_EDGES
}

__global__ void scanC_kernel(const int* __restrict__ deg,
                             const int* __restrict__ part,
                             int* __restrict__ rowptr, int* __restrict__ pos) {
    __shared__ int s[SCAN_B];
    int t = threadIdx.x;
    int i = blockIdx.x * SCAN_B + t;
    int d = (i < N_NODES) ? deg[i] : 0;
    s[t] = d;
    __syncthreads();
    for (int off = 1; off < SCAN_B; off <<= 1) {
        int v = 0;
        if (t >= off) v = s[t - off];
        __syncthreads();
        if (t >= off) s[t] += v;
        __syncthreads();
    }
    if (i < N_NODES) {
        int r = part[blockIdx.x] + s[t] - d;   // exclusive
        rowptr[i] = r;
        pos[i] = r;
    }
}

__global__ void fill_kernel(const int* __restrict__ row, const int* __restrict__ col,
                            const float* __restrict__ ew, int* __restrict__ pos,
                            int2* __restrict__ pairs) {
    int e = blockIdx.x * blockDim.x + threadIdx.x;
    if (e >= N_EDGES) return;
    int idx = atomicAdd(&pos[row[e]], 1);
    pairs[idx] = make_int2(col[e], __float_as_int(ew[e]));
}

// ---------------------------------------------------------------------------
// CSR aggregation from the BF16 h-table. Free-running 256-thread blocks, no
// barrier (R6 lesson). 2-way edge unroll for memory-level parallelism.
// LSM: fuse +b3 and log_softmax (16-lane shuffle groups), fp32 output.
// ---------------------------------------------------------------------------
template <int D, bool LSM>
__global__ void agg_csr_kernel(const unsigned short* __restrict__ h,
                               const int* __restrict__ rowptr,
                               const int2* __restrict__ pairs,
                               float* __restrict__ out,
                               const float* __restrict__ b3) {
    constexpr int G = D / 4;
    int t = blockIdx.x * blockDim.x + threadIdx.x;
    if (t >= N_NODES * G) return;
    int n = t / G, g = t % G;
    int beg = rowptr[n], end = rowptr[n + 1];
    float4 acc = make_float4(0.f, 0.f, 0.f, 0.f);
    float4 acc2 = make_float4(0.f, 0.f, 0.f, 0.f);
    int i = beg;
    for (; i + 1 < end; i += 2) {
        int2 p0 = pairs[i];
        int2 p1 = pairs[i + 1];
        ushort4 u0 = *(const ushort4*)(h + (size_t)p0.x * D + g * 4);
        ushort4 u1 = *(const ushort4*)(h + (size_t)p1.x * D + g * 4);
        float w0 = __int_as_float(p0.y), w1 = __int_as_float(p1.y);
        acc.x += w0 * b2f(u0.x); acc.y += w0 * b2f(u0.y);
        acc.z += w0 * b2f(u0.z); acc.w += w0 * b2f(u0.w);
        acc2.x += w1 * b2f(u1.x); acc2.y += w1 * b2f(u1.y);
        acc2.z += w1 * b2f(u1.z); acc2.w += w1 * b2f(u1.w);
    }
    if (i < end) {
        int2 p = pairs[i];
        float w = __int_as_float(p.y);
        ushort4 u = *(const ushort4*)(h + (size_t)p.x * D + g * 4);
        acc.x += w * b2f(u.x); acc.y += w * b2f(u.y);
        acc.z += w * b2f(u.z); acc.w += w * b2f(u.w);
    }
    acc.x += acc2.x; acc.y += acc2.y; acc.z += acc2.z; acc.w += acc2.w;

    if (LSM) {
        float4 bv = *(const float4*)(b3 + g * 4);
        float4 v = make_float4(acc.x + bv.x, acc.y + bv.y,
                               acc.z + bv.z, acc.w + bv.w);
        float m = fmaxf(fmaxf(v.x, v.y), fmaxf(v.z, v.w));
#pragma unroll
        for (int mask = 1; mask < 16; mask <<= 1)
            m = fmaxf(m, __shfl_xor(m, mask, 16));
        float s = expf(v.x - m) + expf(v.y - m) + expf(v.z - m) + expf(v.w - m);
#pragma unroll
        for (int mask = 1; mask < 16; mask <<= 1)
            s += __shfl_xor(s, mask, 16);
        float l = m + logf(s);
        *(float4*)(out + (size_t)n * D + g * 4) =
            make_float4(v.x - l, v.y - l, v.z - l, v.w - l);
    } else {
        *(float4*)(out + (size_t)n * D + g * 4) = acc;
    }
}

// ---------------------------------------------------------------------------
// BN stats (standalone, register-accumulation). Block = 384 threads =
// 16 rows x 24 groups; thread owns 4 fixed channels.
// ---------------------------------------------------------------------------
#define STATS_BLOCKS 250

template <int D>
__global__ void bn_stats_kernel(const float* __restrict__ a,
                                float* __restrict__ sums, int N) {
    constexpr int G = D / 4;       // 24
    constexpr int ROWS = 384 / G;  // 16
    int t = threadIdx.x;
    int g = t % G, r0 = t / G;
    float4 s4 = make_float4(0.f, 0.f, 0.f, 0.f);
    float4 q4 = make_float4(0.f, 0.f, 0.f, 0.f);
    for (int r = blockIdx.x * ROWS + r0; r < N; r += gridDim.x * ROWS) {
        float4 v = *(const float4*)(a + (size_t)r * D + g * 4);
        s4.x += v.x; s4.y += v.y; s4.z += v.z; s4.w += v.w;
        q4.x += v.x * v.x; q4.y += v.y * v.y; q4.z += v.z * v.z; q4.w += v.w * v.w;
    }
    __shared__ __align__(16) float sh[2 * ROWS * D];
    *(float4*)&sh[r0 * D + g * 4] = s4;
    *(float4*)&sh[ROWS * D + r0 * D + g * 4] = q4;
    __syncthreads();
    if (t < D) {
        float s0 = 0.f, s1 = 0.f;
#pragma unroll
        for (int k = 0; k < ROWS; ++k) {
            s0 += sh[k * D + t];
            s1 += sh[ROWS * D + k * D + t];
        }
        atomicAdd(&sums[t], s0);
        atomicAdd(&sums[D + t], s1);
    }
}

extern "C" void kernel_launch(void* const* d_in, const int* in_sizes, int n_in,
                              void* d_out, int out_size, void* d_ws, size_t ws_size,
                              hipStream_t stream) {
    const float* x   = (const float*)d_in[0];
    const float* ew  = (const float*)d_in[1];
    const int*   row = (const int*)d_in[2];
    const int*   col = (const int*)d_in[3];
    const float* W1  = (const float*)d_in[4];
    // b1 = d_in[5], b2 = d_in[7]: cancel inside BatchNorm (see gemm_mfma).
    const float* W2  = (const float*)d_in[6];
    const float* W3  = (const float*)d_in[8];
    const float* b3  = (const float*)d_in[9];
    const float* g1  = (const float*)d_in[10];
    const float* be1 = (const float*)d_in[11];
    const float* g2  = (const float*)d_in[12];
    const float* be2 = (const float*)d_in[13];
    float* out = (float*)d_out;

    // Workspace: B fp32[N*96] | A bf16[N*96] | stats1[192] | stats2[192] |
    //   Wt1 bf16[96*128] | Wt2 bf16[96*96] | Wt3 bf16[64*96] |
    //   pairs[E int2] | rowptr[N+1] | deg[N] | pos[N] | part[SCAN_NB]
    float*          B      = (float*)d_ws;
    unsigned short* A      = (unsigned short*)(B + (size_t)N_NODES * HID_C);
    float*          stats1 = (float*)(A + (size_t)N_NODES * HID_C);
    float*          stats2 = stats1 + 2 * HID_C;
    unsigned short* Wt1    = (unsigned short*)(stats2 + 2 * HID_C);
    unsigned short* Wt2    = Wt1 + IN_C * HID_C;
    unsigned short* Wt3    = Wt2 + HID_C * HID_C;
    int2*           pairs  = (int2*)(Wt3 + HID_C * OUT_C);
    int*            rowptr = (int*)(pairs + N_EDGES);
    int*            deg    = rowptr + (N_NODES + 1);
    int*            pos    = deg + N_NODES;
    int*            part   = pos + N_NODES;

    const int T = 256;
    const int gridE   = (N_EDGES + T - 1) / T;
    const int gridA96 = (N_NODES * (HID_C / 4) + T - 1) / T;
    const int gridA64 = (N_NODES * (OUT_C / 4) + T - 1) / T;
    const int gridG   = (N_NODES + 63) / 64;

    // ---- Weight prep (bf16 transpose) + CSR build + stats zero ----
    wprep_kernel<IN_C, HID_C><<<(IN_C * HID_C + T - 1) / T, T, 0, stream>>>(W1, Wt1);
    wprep_kernel<HID_C, HID_C><<<(HID_C * HID_C + T - 1) / T, T, 0, stream>>>(W2, Wt2);
    wprep_kernel<HID_C, OUT_C><<<(HID_C * OUT_C + T - 1) / T, T, 0, stream>>>(W3, Wt3);
    hipMemsetAsync(deg, 0, N_NODES * sizeof(int), stream);
    hipMemsetAsync(stats1, 0, 4 * HID_C * sizeof(float), stream);
    hist_kernel<<<gridE, T, 0, stream>>>(row, deg);
    scanA_kernel<<<SCAN_NB, SCAN_B, 0, stream>>>(deg, part);
    scanB_kernel<<<1, SCAN_B, 0, stream>>>(part, rowptr);
    scanC_kernel<<<SCAN_NB, SCAN_B, 0, stream>>>(deg, part, rowptr, pos);
    fill_kernel<<<gridE, T, 0, stream>>>(row, col, ew, pos, pairs);

    // ---- Layer 1: MFMA GCNConv(128->96) -> bf16 A; agg -> fp32 B; stats ----
    gemm_mfma<IN_C, HID_C, false><<<gridG, T, 0, stream>>>(
        x, Wt1, nullptr, nullptr, nullptr, A, N_NODES);
    agg_csr_kernel<HID_C, false><<<gridA96, T, 0, stream>>>(
        A, rowptr, pairs, B, nullptr);
    bn_stats_kernel<HID_C><<<STATS_BLOCKS, 384, 0, stream>>>(B, stats1, N_NODES);

    // ---- Layer 2: gemm fuses BN1 finalize+apply+ReLU; agg; BN2 stats ----
    gemm_mfma<HID_C, HID_C, true><<<gridG, T, 0, stream>>>(
        B, Wt2, stats1, g1, be1, A, N_NODES);
    agg_csr_kernel<HID_C, false><<<gridA96, T, 0, stream>>>(
        A, rowptr, pairs, B, nullptr);
    bn_stats_kernel<HID_C><<<STATS_BLOCKS, 384, 0, stream>>>(B, stats2, N_NODES);

    // ---- Layer 3: gemm fuses BN2; agg fuses +b3 and log_softmax -> out ----
    gemm_mfma<HID_C, OUT_C, true><<<gridG, T, 0, stream>>>(
        B, Wt3, stats2, g2, be2, A, N_NODES);
    agg_csr_kernel<OUT_C, true><<<gridA64, T, 0, stream>>>(
        A, rowptr, pairs, out, b3);
}